// Round 5
// baseline (681.483 us; speedup 1.0000x reference)
//
#include <hip/hip_runtime.h>

#define DF 128
#define CAP 24   // slot capacity; Poisson(3) P(deg>=24)*300K ~ 7e-9

typedef __bf16 bf16x8 __attribute__((ext_vector_type(8)));
typedef float f32x4 __attribute__((ext_vector_type(4)));
typedef unsigned short ushort8v __attribute__((ext_vector_type(8)));

__device__ __forceinline__ unsigned short f2bf(float f) {
    union { float f; unsigned int u; } v; v.f = f;
    unsigned int r = v.u + 0x7FFFu + ((v.u >> 16) & 1u);   // round-to-nearest-even
    return (unsigned short)(r >> 16);
}
__device__ __forceinline__ float bf2f(unsigned short u) {
    union { unsigned int u; float f; } v; v.u = ((unsigned int)u) << 16;
    return v.f;
}

// ===========================================================================
// Fused prep: fill + pack + convert in ONE dispatch, SECTION-STRIPED.
//
// R5 theory: fill's 900K device-scope atomics are a fixed-throughput wall at
// the coherence point (~72 us standalone, all pipes idle); convert is a
// ~33 us streaming pass. In launch order they serialize (105 ~= 72+33)
// because fill blocks occupy all wave slots first. The transpose block remap
//   b = (bid&31)*C + (bid>>5)
// issues fill blocks uniformly throughout the dispatch so the atomic wall is
// serviced concurrently with convert's streaming -> prep ~= max(72, 33).
//
// fill additionally batches 4 edges/thread (4 independent atomic->store
// chains in flight; helps if queue-limited, neutral under the wall model).
// ===========================================================================
__global__ __launch_bounds__(256)
void prep_kernel(// fill args
                 const int* __restrict__ ei_calls, int E1,
                 const int* __restrict__ ei_belongs, int E2,
                 const int* __restrict__ ei_has, int E3,
                 int* __restrict__ cnt, int* __restrict__ slots,
                 // convert args
                 const float* __restrict__ x_service,
                 const float* __restrict__ x_endpoint,
                 unsigned short* __restrict__ xb_svc,
                 unsigned short* __restrict__ xb_ep,
                 int n_svc, int n_ep,
                 // pack args
                 const float* __restrict__ Wl_calls, const float* __restrict__ Wr_calls,
                 const float* __restrict__ Wl_belongs, const float* __restrict__ Wr_belongs,
                 const float* __restrict__ Wl_has, const float* __restrict__ Wr_has,
                 const float* __restrict__ bl_calls, const float* __restrict__ bl_belongs,
                 const float* __restrict__ bl_has,
                 unsigned short* __restrict__ Bp_svc, unsigned short* __restrict__ Bp_ep,
                 float* __restrict__ bias_svc, float* __restrict__ bias_ep,
                 int B_fill, int B_pack, int B_tot)
{
    // transpose remap: consecutive launched blocks hit sections interleaved
    const int C = (B_tot + 31) >> 5;
    int b = (blockIdx.x & 31) * C + (blockIdx.x >> 5);
    if (b >= B_tot) return;

    if (b < B_fill) {
        // ------------------------- fill section -------------------------
        // 4 edges per thread: 4 independent atomicAdd->store chains.
        int Etot = E1 + E2 + E3;
        int e0 = (b * 256 + threadIdx.x) * 4;
        int gl[4], sv[4];
#pragma unroll
        for (int j = 0; j < 4; ++j) {
            int e = e0 + j;
            if (e < Etot) {
                int s, d, base;
                if (e < E1)           { s = ei_calls[e]; d = ei_calls[E1 + e]; base = 0; }
                else if (e < E1 + E2) { int el = e - E1; s = ei_belongs[el]; d = ei_belongs[E2 + el]; base = n_svc; }
                else                  { int el = e - E1 - E2; s = ei_has[el]; d = ei_has[E3 + el]; base = 2 * n_svc; }
                gl[j] = base + d; sv[j] = s;
            } else gl[j] = -1;
        }
        int pos[4];
#pragma unroll
        for (int j = 0; j < 4; ++j)
            if (gl[j] >= 0) pos[j] = atomicAdd(cnt + gl[j], 1);
#pragma unroll
        for (int j = 0; j < 4; ++j)
            if (gl[j] >= 0 && pos[j] < CAP)
                slots[(size_t)gl[j] * CAP + pos[j]] = sv[j];
        return;
    }
    b -= B_fill;

    if (b < B_pack) {
        // ------------------------- pack section -------------------------
        int t = b * 256 + threadIdx.x;
        const int SV = 12 * 8 * 64 * 8;   // 49152
        const int EPN = 8 * 8 * 64 * 8;   // 32768
        if (t < SV) {
            int j = t & 7, lane = (t >> 3) & 63, ct = (t >> 9) & 7, kt = t >> 12;
            int k = kt * 32 + (lane >> 4) * 8 + j;
            int n = ct * 16 + (lane & 15);
            float v;
            if (k < 128)       v = Wl_calls[n * DF + k];
            else if (k < 256)  v = Wl_belongs[n * DF + (k - 128)];
            else               v = Wr_calls[n * DF + (k - 256)] + Wr_belongs[n * DF + (k - 256)];
            Bp_svc[t] = f2bf(v);
        } else if (t < SV + EPN) {
            int t2 = t - SV;
            int j = t2 & 7, lane = (t2 >> 3) & 63, ct = (t2 >> 9) & 7, kt = t2 >> 12;
            int k = kt * 32 + (lane >> 4) * 8 + j;
            int n = ct * 16 + (lane & 15);
            float v = (k < 128) ? Wl_has[n * DF + k] : Wr_has[n * DF + (k - 128)];
            Bp_ep[t2] = f2bf(v);
        }
        if (t < 128) bias_svc[t] = bl_calls[t] + bl_belongs[t];
        else if (t < 256) bias_ep[t - 128] = bl_has[t - 128];
        return;
    }
    b -= B_pack;

    // ------------------------- convert section -------------------------
    int tid = b * 256 + threadIdx.x;
    int node = tid >> 5;
    int c4 = (tid & 31) << 2;
    if (node < n_svc) {
        float4 v = *reinterpret_cast<const float4*>(x_service + (size_t)node * DF + c4);
        ushort4 o; o.x = f2bf(v.x); o.y = f2bf(v.y); o.z = f2bf(v.z); o.w = f2bf(v.w);
        *reinterpret_cast<ushort4*>(xb_svc + (size_t)node * DF + c4) = o;
    } else if (node < n_svc + n_ep) {
        int ne = node - n_svc;
        float4 v = *reinterpret_cast<const float4*>(x_endpoint + (size_t)ne * DF + c4);
        ushort4 o; o.x = f2bf(v.x); o.y = f2bf(v.y); o.z = f2bf(v.z); o.w = f2bf(v.w);
        *reinterpret_cast<ushort4*>(xb_ep + (size_t)ne * DF + c4) = o;
    }
}

// ===========================================================================
// FUSED gather-mean + MFMA GEMM body. One block = 64 dst rows x 128 cols,
// 512 threads = 8 waves. (Same structure as R4; now a device function so
// svc and ep are block-interleaved in ONE dispatch -> ep gather-latency
// waves overlap svc MFMA waves, and one launch gap is removed.)
// ===========================================================================
template <int MODE>
__device__ __forceinline__ void fused_body(
        int bid, unsigned short* __restrict__ smean,
        const unsigned short* __restrict__ xb_svc,
        const unsigned short* __restrict__ xb_ep,
        const int* __restrict__ cnt,
        const int* __restrict__ slots,
        const unsigned short* __restrict__ Bpack,
        const float* __restrict__ bias,
        float* __restrict__ out,
        int n_svc, int n_ep)
{
    constexpr int MK      = (MODE == 0) ? 256 : 128;  // mean cols in LDS
    constexpr int KSTEPS  = (MODE == 0) ? 12 : 8;
    constexpr int MKSTEPS = MK / 32;                  // K-steps served by LDS
    constexpr int ROWS    = 64;
    constexpr int NG      = (MODE == 0) ? 2 * ROWS : ROWS;  // 128 / 64
    constexpr int NI      = NG * 16 / 512;                  // 4 / 2

    const int M = (MODE == 0) ? n_svc : n_ep;
    const int row_base = bid * ROWS;

    // ---------------- phase 1: gather + mean into LDS ----------------
    const int lane16 = threadIdx.x & 15;
    const int c8 = lane16 << 3;

    int degA[NI];
    int gA[NI];
    const unsigned short* srcA[NI];
    unsigned short* dstA[NI];

#pragma unroll
    for (int it = 0; it < NI; ++it) {
        int gl   = (it * 512 + threadIdx.x) >> 4;   // [0, NG)
        int node = gl & (ROWS - 1);
        int t    = gl / ROWS;                       // type (svc: 0=calls,1=belongs)
        int chunk = lane16 + t * 16;
        dstA[it] = smean + node * MK + ((chunk ^ (node & 7)) << 3);
        int gnode = row_base + node;
        int gn_c  = gnode < M ? gnode : M - 1;      // clamped: valid cnt addr
        int g;
        if (MODE == 0) {
            g = (t == 0) ? gn_c : (n_svc + gn_c);
            srcA[it] = (t == 0) ? xb_svc : xb_ep;
        } else {
            g = 2 * n_svc + gn_c;
            srcA[it] = xb_svc;
        }
        gA[it] = g;
        int d = cnt[g];                              // NI independent loads
        if (gnode >= M) d = 0;
        if (d > CAP) d = CAP;
        degA[it] = d;
    }

    int4 s4[NI];
#pragma unroll
    for (int it = 0; it < NI; ++it)                  // NI independent 16B loads
        s4[it] = *reinterpret_cast<const int4*>(slots + (size_t)gA[it] * CAP);

    // sanitized fast-path indices: never form a wild address
    int idxA[NI][4];
#pragma unroll
    for (int it = 0; it < NI; ++it) {
        int d = degA[it];
        idxA[it][0] = (0 < d) ? s4[it].x : 0;
        idxA[it][1] = (1 < d) ? s4[it].y : 0;
        idxA[it][2] = (2 < d) ? s4[it].z : 0;
        idxA[it][3] = (3 < d) ? s4[it].w : 0;
    }

    // 2-deep gather pipeline over iterations
    ushort8v vb0[4], vb1[4];
#pragma unroll
    for (int j = 0; j < 4; ++j)
        vb0[j] = *reinterpret_cast<const ushort8v*>(
            srcA[0] + (size_t)idxA[0][j] * DF + c8);

#pragma unroll
    for (int it = 0; it < NI; ++it) {
        if (it + 1 < NI) {
#pragma unroll
            for (int j = 0; j < 4; ++j) {
                const ushort8v* p = reinterpret_cast<const ushort8v*>(
                    srcA[it + 1] + (size_t)idxA[it + 1][j] * DF + c8);
                if ((it & 1) == 0) vb1[j] = *p; else vb0[j] = *p;
            }
        }
        float acc[8];
#pragma unroll
        for (int q = 0; q < 8; ++q) acc[q] = 0.f;
#pragma unroll
        for (int j = 0; j < 4; ++j) {
            if (j < degA[it]) {
                ushort8v v = ((it & 1) == 0) ? vb0[j] : vb1[j];
#pragma unroll
                for (int q = 0; q < 8; ++q) acc[q] += bf2f(v[q]);
            }
        }
        if (degA[it] <= 4) {
            float inv = 1.0f / (float)max(degA[it], 1);
            ushort8v o;
#pragma unroll
            for (int q = 0; q < 8; ++q) o[q] = f2bf(acc[q] * inv);
            *reinterpret_cast<ushort8v*>(dstA[it]) = o;
        }
    }

    // rare second pass: deg>4 groups recomputed fully (old batch-of-8 order)
#pragma unroll
    for (int it = 0; it < NI; ++it) {
        int deg = degA[it];
        if (deg > 4) {
            const int* sp = slots + (size_t)gA[it] * CAP;
            const unsigned short* src = srcA[it];
            float acc[8];
#pragma unroll
            for (int q = 0; q < 8; ++q) acc[q] = 0.f;
            for (int i0 = 0; i0 < deg; i0 += 8) {
                int idx[8];
#pragma unroll
                for (int j = 0; j < 8; ++j) {
                    int ii = i0 + j;
                    if (ii > deg - 1) ii = deg - 1;   // clamp: dup hits L1
                    idx[j] = sp[ii];
                }
                ushort8v v[8];
#pragma unroll
                for (int j = 0; j < 8; ++j)
                    v[j] = *reinterpret_cast<const ushort8v*>(
                        src + (size_t)idx[j] * DF + c8);
                int nv = deg - i0;
#pragma unroll
                for (int j = 0; j < 8; ++j) {
                    if (j < nv) {
#pragma unroll
                        for (int q = 0; q < 8; ++q) acc[q] += bf2f(v[j][q]);
                    }
                }
            }
            float inv = 1.0f / (float)deg;
            ushort8v o;
#pragma unroll
            for (int q = 0; q < 8; ++q) o[q] = f2bf(acc[q] * inv);
            *reinterpret_cast<ushort8v*>(dstA[it]) = o;
        }
    }
    __syncthreads();

    // ---------------- phase 2: MFMA ----------------
    // 8 waves: wr = wave>>2 in [0,2) owns rows wr*32..wr*32+31,
    // wc = wave&3 in [0,4) owns col-tiles wc*2, wc*2+1.
    const int lane = threadIdx.x & 63;
    const int wave = threadIdx.x >> 6;
    const int wr   = wave >> 2;
    const int wc   = wave & 3;
    const int quad = lane >> 4;
    const int lc   = lane & 15;
    const int m0l  = wr * 32 + lc;
    const int m1l  = m0l + 16;
    int m0 = row_base + m0l; if (m0 > M - 1) m0 = M - 1;   // clamp for xb reads
    int m1 = row_base + m1l; if (m1 > M - 1) m1 = M - 1;

    const unsigned short* xb_dst = (MODE == 0) ? xb_svc : xb_ep;
    const unsigned short* Xp0 = xb_dst + (size_t)m0 * DF + quad * 8;
    const unsigned short* Xp1 = xb_dst + (size_t)m1 * DF + quad * 8;
    const unsigned short* Bp  = Bpack + lane * 8 + (wc * 2) * 512;

    f32x4 acc0[2], acc1[2];
#pragma unroll
    for (int ct = 0; ct < 2; ++ct) {
        acc0[ct] = (f32x4){0.f, 0.f, 0.f, 0.f};
        acc1[ct] = (f32x4){0.f, 0.f, 0.f, 0.f};
    }

#pragma unroll
    for (int kt = 0; kt < KSTEPS; ++kt) {
        bf16x8 af0, af1;
        if (kt < MKSTEPS) {
            int c = kt * 4 + quad;   // 16 B chunk index
            af0 = *reinterpret_cast<const bf16x8*>(
                smean + m0l * MK + ((c ^ (m0l & 7)) << 3));
            af1 = *reinterpret_cast<const bf16x8*>(
                smean + m1l * MK + ((c ^ (m1l & 7)) << 3));
        } else {
            af0 = *reinterpret_cast<const bf16x8*>(Xp0 + (kt - MKSTEPS) * 32);
            af1 = *reinterpret_cast<const bf16x8*>(Xp1 + (kt - MKSTEPS) * 32);
        }
        const unsigned short* bptr = Bp + (size_t)kt * 8 * 512;
#pragma unroll
        for (int ct = 0; ct < 2; ++ct) {
            bf16x8 bf = *reinterpret_cast<const bf16x8*>(bptr + ct * 512);
            acc0[ct] = __builtin_amdgcn_mfma_f32_16x16x32_bf16(af0, bf, acc0[ct], 0, 0, 0);
            acc1[ct] = __builtin_amdgcn_mfma_f32_16x16x32_bf16(af1, bf, acc1[ct], 0, 0, 0);
        }
    }

    float bc[2];
#pragma unroll
    for (int ct = 0; ct < 2; ++ct) bc[ct] = bias[(wc * 2 + ct) * 16 + lc];

    // C/D layout: col = (wc*2+ct)*16 + lc, row = base + quad*4 + r
    const int row0 = row_base + wr * 32;
#pragma unroll
    for (int half = 0; half < 2; ++half) {
        int orow0 = row0 + half * 16 + quad * 4;
        f32x4* accp = half ? acc1 : acc0;
#pragma unroll
        for (int r = 0; r < 4; ++r) {
            int orow = orow0 + r;
            if (orow < M) {
                float* op = out + (size_t)orow * DF + wc * 32 + lc;
#pragma unroll
                for (int ct = 0; ct < 2; ++ct) op[ct * 16] = accp[ct][r] + bc[ct];
            }
        }
    }
}

// Merged dispatch: even blocks -> svc (MODE 0), odd blocks -> ep (MODE 1),
// leftovers (if grids unequal) appended to whichever is larger.
__global__ __launch_bounds__(512, 4)
void fused_gemm_all(const unsigned short* __restrict__ xb_svc,
                    const unsigned short* __restrict__ xb_ep,
                    const int* __restrict__ cnt,
                    const int* __restrict__ slots,
                    const unsigned short* __restrict__ Bp_svc,
                    const unsigned short* __restrict__ Bp_ep,
                    const float* __restrict__ bias_svc,
                    const float* __restrict__ bias_ep,
                    float* __restrict__ out_svc,
                    float* __restrict__ out_ep,
                    int n_svc, int n_ep, int G0, int G1)
{
    __shared__ unsigned short smean[64 * 256];   // 32 KB (MODE1 uses half)

    int b = blockIdx.x;
    int Gm = (G0 < G1) ? G0 : G1;
    int mode, idx;
    if (b < 2 * Gm) { mode = b & 1; idx = b >> 1; }
    else {
        int r = b - 2 * Gm;
        if (G0 > G1) { mode = 0; idx = Gm + r; }
        else         { mode = 1; idx = Gm + r; }
    }

    if (mode == 0)
        fused_body<0>(idx, smean, xb_svc, xb_ep, cnt, slots,
                      Bp_svc, bias_svc, out_svc, n_svc, n_ep);
    else
        fused_body<1>(idx, smean, xb_svc, xb_ep, cnt, slots,
                      Bp_ep, bias_ep, out_ep, n_svc, n_ep);
}

// ---------------------------------------------------------------------------
extern "C" void kernel_launch(void* const* d_in, const int* in_sizes, int n_in,
                              void* d_out, int out_size, void* d_ws, size_t ws_size,
                              hipStream_t stream)
{
    const float* x_service  = (const float*)d_in[0];
    const float* x_endpoint = (const float*)d_in[1];
    const int*   ei_calls   = (const int*)d_in[2];
    const int*   ei_has     = (const int*)d_in[3];
    const int*   ei_belongs = (const int*)d_in[4];
    const float* Wl_calls   = (const float*)d_in[5];
    const float* bl_calls   = (const float*)d_in[6];
    const float* Wr_calls   = (const float*)d_in[7];
    const float* Wl_has     = (const float*)d_in[8];
    const float* bl_has     = (const float*)d_in[9];
    const float* Wr_has     = (const float*)d_in[10];
    const float* Wl_belongs = (const float*)d_in[11];
    const float* bl_belongs = (const float*)d_in[12];
    const float* Wr_belongs = (const float*)d_in[13];

    const int n_svc = in_sizes[0] / DF;
    const int n_ep  = in_sizes[1] / DF;
    const int E1 = in_sizes[2] / 2;   // calls
    const int E3 = in_sizes[3] / 2;   // has
    const int E2 = in_sizes[4] / 2;   // belongs
    const int Etot = E1 + E2 + E3;
    const int NT = 2 * n_svc + n_ep;

    int* wsi = (int*)d_ws;
    size_t oi = 0;
    int* cnt   = wsi + oi; oi += NT;
    int* slots = wsi + oi; oi += (size_t)NT * CAP;
    oi = (oi + 3) & ~(size_t)3;   // 16B align

    unsigned short* wsu = (unsigned short*)(wsi + oi);
    size_t ou = 0;
    unsigned short* xb_svc = wsu + ou; ou += (size_t)n_svc * DF;
    unsigned short* xb_ep  = wsu + ou; ou += (size_t)n_ep * DF;
    unsigned short* Bp_svc = wsu + ou; ou += 12 * 8 * 64 * 8;
    unsigned short* Bp_ep  = wsu + ou; ou += 8 * 8 * 64 * 8;
    ou = (ou + 7) & ~(size_t)7;
    float* bias_svc = (float*)(wsu + ou);
    float* bias_ep  = bias_svc + DF;

    // only the degree counters need zero-init
    hipMemsetAsync(cnt, 0, (size_t)NT * sizeof(int), stream);

    const int B_fill = (Etot + 1023) / 1024;   // 4 edges/thread
    const int B_pack = (12 * 8 * 64 * 8 + 8 * 8 * 64 * 8 + 255) / 256;
    const int B_conv = (int)(((size_t)(n_svc + n_ep) * 32 + 255) / 256);
    const int B_tot  = B_fill + B_pack + B_conv;
    const int C      = (B_tot + 31) >> 5;      // transpose-stripe columns

    prep_kernel<<<C * 32, 256, 0, stream>>>(
        ei_calls, E1, ei_belongs, E2, ei_has, E3, cnt, slots,
        x_service, x_endpoint, xb_svc, xb_ep, n_svc, n_ep,
        Wl_calls, Wr_calls, Wl_belongs, Wr_belongs, Wl_has, Wr_has,
        bl_calls, bl_belongs, bl_has, Bp_svc, Bp_ep, bias_svc, bias_ep,
        B_fill, B_pack, B_tot);

    float* out_svc = (float*)d_out;
    float* out_ep  = out_svc + (size_t)n_svc * DF;

    const int G0 = (n_svc + 63) / 64;
    const int G1 = (n_ep + 63) / 64;

    fused_gemm_all<<<G0 + G1, 512, 0, stream>>>(
        xb_svc, xb_ep, cnt, slots, Bp_svc, Bp_ep,
        bias_svc, bias_ep, out_svc, out_ep, n_svc, n_ep, G0, G1);
}

// Round 6
// 354.176 us; speedup vs baseline: 1.9241x; 1.9241x over previous
//
#include <hip/hip_runtime.h>

#define DF 128
#define CAP 24   // slot capacity; Poisson(3) P(deg>=24)*300K ~ 7e-9

typedef __bf16 bf16x8 __attribute__((ext_vector_type(8)));
typedef float f32x4 __attribute__((ext_vector_type(4)));
typedef unsigned short ushort8v __attribute__((ext_vector_type(8)));

__device__ __forceinline__ unsigned short f2bf(float f) {
    union { float f; unsigned int u; } v; v.f = f;
    unsigned int r = v.u + 0x7FFFu + ((v.u >> 16) & 1u);   // round-to-nearest-even
    return (unsigned short)(r >> 16);
}
__device__ __forceinline__ float bf2f(unsigned short u) {
    union { unsigned int u; float f; } v; v.u = ((unsigned int)u) << 16;
    return v.f;
}

// ===========================================================================
// Fused prep, R6 structure: ONE dispatch, grid = B_conv blocks; every block
// does its convert slice; blocks [0,B_fill) ALSO process one edge/thread;
// the last B_pack blocks ALSO pack weights.
//
// Why merged duties instead of section-striping (R5 post-mortem): workgroups
// place in launch order, so any section ordering serializes fill's 14K waves
// against convert's 25K blocks (R4: 105 ~= 72+33). R5's stripe+multi-atomic
// collapsed concurrency (occupancy 9.8%, 4 serial atomic round-trips per
// thread) -> 413 us. Here fill keeps EXACTLY R4's shape - one device-scope
// atomicAdd per thread, 900K threads - but every atomic issuer is resident
// within the first few us because it rides in the convert blocks. The atomic
// is issued FIRST, the slot scatter-store LAST, with convert's independent
// streaming in between to hide the atomic round-trip.
// Expected: prep ~= max(fill wall ~72, convert ~33) + eps ~= 80 us.
// ===========================================================================
__global__ __launch_bounds__(256)
void prep_kernel(// fill args
                 const int* __restrict__ ei_calls, int E1,
                 const int* __restrict__ ei_belongs, int E2,
                 const int* __restrict__ ei_has, int E3,
                 int* __restrict__ cnt, int* __restrict__ slots,
                 // convert args
                 const float* __restrict__ x_service,
                 const float* __restrict__ x_endpoint,
                 unsigned short* __restrict__ xb_svc,
                 unsigned short* __restrict__ xb_ep,
                 int n_svc, int n_ep,
                 // pack args
                 const float* __restrict__ Wl_calls, const float* __restrict__ Wr_calls,
                 const float* __restrict__ Wl_belongs, const float* __restrict__ Wr_belongs,
                 const float* __restrict__ Wl_has, const float* __restrict__ Wr_has,
                 const float* __restrict__ bl_calls, const float* __restrict__ bl_belongs,
                 const float* __restrict__ bl_has,
                 unsigned short* __restrict__ Bp_svc, unsigned short* __restrict__ Bp_ep,
                 float* __restrict__ bias_svc, float* __restrict__ bias_ep,
                 int B_fill, int B_pack, int B_conv)
{
    const int b = blockIdx.x;
    const int tid = threadIdx.x;

    // ---- fill duty, part 1: decode + atomic ticket (issued first) ----
    int g = -1, sv = 0, pos = 0;
    if (b < B_fill) {
        int e = b * 256 + tid;
        int Etot = E1 + E2 + E3;
        if (e < Etot) {
            int s, d, base;
            if (e < E1)           { s = ei_calls[e]; d = ei_calls[E1 + e]; base = 0; }
            else if (e < E1 + E2) { int el = e - E1; s = ei_belongs[el]; d = ei_belongs[E2 + el]; base = n_svc; }
            else                  { int el = e - E1 - E2; s = ei_has[el]; d = ei_has[E3 + el]; base = 2 * n_svc; }
            g = base + d; sv = s;
            pos = atomicAdd(cnt + g, 1);
        }
    }

    // ---- convert duty (all blocks; independent of the atomic in flight) ----
    {
        int tid2 = b * 256 + tid;
        int node = tid2 >> 5;
        int c4 = (tid2 & 31) << 2;
        if (node < n_svc) {
            float4 v = *reinterpret_cast<const float4*>(x_service + (size_t)node * DF + c4);
            ushort4 o; o.x = f2bf(v.x); o.y = f2bf(v.y); o.z = f2bf(v.z); o.w = f2bf(v.w);
            *reinterpret_cast<ushort4*>(xb_svc + (size_t)node * DF + c4) = o;
        } else if (node < n_svc + n_ep) {
            int ne = node - n_svc;
            float4 v = *reinterpret_cast<const float4*>(x_endpoint + (size_t)ne * DF + c4);
            ushort4 o; o.x = f2bf(v.x); o.y = f2bf(v.y); o.z = f2bf(v.z); o.w = f2bf(v.w);
            *reinterpret_cast<ushort4*>(xb_ep + (size_t)ne * DF + c4) = o;
        }
    }

    // ---- pack duty (last B_pack blocks) ----
    int bp = b - (B_conv - B_pack);
    if (bp >= 0) {
        int t = bp * 256 + tid;
        const int SV = 12 * 8 * 64 * 8;   // 49152
        const int EPN = 8 * 8 * 64 * 8;   // 32768
        if (t < SV) {
            int j = t & 7, lane = (t >> 3) & 63, ct = (t >> 9) & 7, kt = t >> 12;
            int k = kt * 32 + (lane >> 4) * 8 + j;
            int n = ct * 16 + (lane & 15);
            float v;
            if (k < 128)       v = Wl_calls[n * DF + k];
            else if (k < 256)  v = Wl_belongs[n * DF + (k - 128)];
            else               v = Wr_calls[n * DF + (k - 256)] + Wr_belongs[n * DF + (k - 256)];
            Bp_svc[t] = f2bf(v);
        } else if (t < SV + EPN) {
            int t2 = t - SV;
            int j = t2 & 7, lane = (t2 >> 3) & 63, ct = (t2 >> 9) & 7, kt = t2 >> 12;
            int k = kt * 32 + (lane >> 4) * 8 + j;
            int n = ct * 16 + (lane & 15);
            float v = (k < 128) ? Wl_has[n * DF + k] : Wr_has[n * DF + (k - 128)];
            Bp_ep[t2] = f2bf(v);
        }
        if (t < 128) bias_svc[t] = bl_calls[t] + bl_belongs[t];
        else if (t < 256) bias_ep[t - 128] = bl_has[t - 128];
    }

    // ---- fill duty, part 2: slot scatter-store (atomic result consumed) ----
    if (g >= 0 && pos < CAP)
        slots[(size_t)g * CAP + pos] = sv;
}

// ===========================================================================
// FUSED gather-mean + MFMA GEMM. One block = 64 dst rows x 128 out cols,
// 512 threads = 8 waves. (Identical to the R4 kernel that measured 366 us
// total with both fused dispatches <= 102 us.)
// ===========================================================================
template <int MODE>
__global__ __launch_bounds__(512, 4)
void fused_gemm(const unsigned short* __restrict__ xb_svc,
                const unsigned short* __restrict__ xb_ep,
                const int* __restrict__ cnt,
                const int* __restrict__ slots,
                const unsigned short* __restrict__ Bpack,
                const float* __restrict__ bias,
                float* __restrict__ out,
                int n_svc, int n_ep)
{
    constexpr int MK      = (MODE == 0) ? 256 : 128;  // mean cols in LDS
    constexpr int KSTEPS  = (MODE == 0) ? 12 : 8;
    constexpr int MKSTEPS = MK / 32;                  // K-steps served by LDS
    constexpr int ROWS    = 64;
    constexpr int NG      = (MODE == 0) ? 2 * ROWS : ROWS;  // 128 / 64
    constexpr int NI      = NG * 16 / 512;                  // 4 / 2

    __shared__ unsigned short smean[ROWS * MK];       // svc: 32 KB, ep: 16 KB

    const int M = (MODE == 0) ? n_svc : n_ep;
    const int row_base = blockIdx.x * ROWS;

    // ---------------- phase 1: gather + mean into LDS ----------------
    const int lane16 = threadIdx.x & 15;
    const int c8 = lane16 << 3;

    int degA[NI];
    int gA[NI];
    const unsigned short* srcA[NI];
    unsigned short* dstA[NI];

#pragma unroll
    for (int it = 0; it < NI; ++it) {
        int gl   = (it * 512 + threadIdx.x) >> 4;   // [0, NG)
        int node = gl & (ROWS - 1);
        int t    = gl / ROWS;                       // type (svc: 0=calls,1=belongs)
        int chunk = lane16 + t * 16;
        dstA[it] = smean + node * MK + ((chunk ^ (node & 7)) << 3);
        int gnode = row_base + node;
        int gn_c  = gnode < M ? gnode : M - 1;      // clamped: valid cnt addr
        int g;
        if (MODE == 0) {
            g = (t == 0) ? gn_c : (n_svc + gn_c);
            srcA[it] = (t == 0) ? xb_svc : xb_ep;
        } else {
            g = 2 * n_svc + gn_c;
            srcA[it] = xb_svc;
        }
        gA[it] = g;
        int d = cnt[g];                              // NI independent loads
        if (gnode >= M) d = 0;
        if (d > CAP) d = CAP;
        degA[it] = d;
    }

    int4 s4[NI];
#pragma unroll
    for (int it = 0; it < NI; ++it)                  // NI independent 16B loads
        s4[it] = *reinterpret_cast<const int4*>(slots + (size_t)gA[it] * CAP);

    // sanitized fast-path indices: never form a wild address
    int idxA[NI][4];
#pragma unroll
    for (int it = 0; it < NI; ++it) {
        int d = degA[it];
        idxA[it][0] = (0 < d) ? s4[it].x : 0;
        idxA[it][1] = (1 < d) ? s4[it].y : 0;
        idxA[it][2] = (2 < d) ? s4[it].z : 0;
        idxA[it][3] = (3 < d) ? s4[it].w : 0;
    }

    // 2-deep gather pipeline over iterations
    ushort8v vb0[4], vb1[4];
#pragma unroll
    for (int j = 0; j < 4; ++j)
        vb0[j] = *reinterpret_cast<const ushort8v*>(
            srcA[0] + (size_t)idxA[0][j] * DF + c8);

#pragma unroll
    for (int it = 0; it < NI; ++it) {
        if (it + 1 < NI) {
#pragma unroll
            for (int j = 0; j < 4; ++j) {
                const ushort8v* p = reinterpret_cast<const ushort8v*>(
                    srcA[it + 1] + (size_t)idxA[it + 1][j] * DF + c8);
                if ((it & 1) == 0) vb1[j] = *p; else vb0[j] = *p;
            }
        }
        float acc[8];
#pragma unroll
        for (int q = 0; q < 8; ++q) acc[q] = 0.f;
#pragma unroll
        for (int j = 0; j < 4; ++j) {
            if (j < degA[it]) {
                ushort8v v = ((it & 1) == 0) ? vb0[j] : vb1[j];
#pragma unroll
                for (int q = 0; q < 8; ++q) acc[q] += bf2f(v[q]);
            }
        }
        if (degA[it] <= 4) {
            float inv = 1.0f / (float)max(degA[it], 1);
            ushort8v o;
#pragma unroll
            for (int q = 0; q < 8; ++q) o[q] = f2bf(acc[q] * inv);
            *reinterpret_cast<ushort8v*>(dstA[it]) = o;
        }
    }

    // rare second pass: deg>4 groups recomputed fully (old batch-of-8 order)
#pragma unroll
    for (int it = 0; it < NI; ++it) {
        int deg = degA[it];
        if (deg > 4) {
            const int* sp = slots + (size_t)gA[it] * CAP;
            const unsigned short* src = srcA[it];
            float acc[8];
#pragma unroll
            for (int q = 0; q < 8; ++q) acc[q] = 0.f;
            for (int i0 = 0; i0 < deg; i0 += 8) {
                int idx[8];
#pragma unroll
                for (int j = 0; j < 8; ++j) {
                    int ii = i0 + j;
                    if (ii > deg - 1) ii = deg - 1;   // clamp: dup hits L1
                    idx[j] = sp[ii];
                }
                ushort8v v[8];
#pragma unroll
                for (int j = 0; j < 8; ++j)
                    v[j] = *reinterpret_cast<const ushort8v*>(
                        src + (size_t)idx[j] * DF + c8);
                int nv = deg - i0;
#pragma unroll
                for (int j = 0; j < 8; ++j) {
                    if (j < nv) {
#pragma unroll
                        for (int q = 0; q < 8; ++q) acc[q] += bf2f(v[j][q]);
                    }
                }
            }
            float inv = 1.0f / (float)deg;
            ushort8v o;
#pragma unroll
            for (int q = 0; q < 8; ++q) o[q] = f2bf(acc[q] * inv);
            *reinterpret_cast<ushort8v*>(dstA[it]) = o;
        }
    }
    __syncthreads();

    // ---------------- phase 2: MFMA ----------------
    // 8 waves: wr = wave>>2 in [0,2) owns rows wr*32..wr*32+31,
    // wc = wave&3 in [0,4) owns col-tiles wc*2, wc*2+1.
    const int lane = threadIdx.x & 63;
    const int wave = threadIdx.x >> 6;
    const int wr   = wave >> 2;
    const int wc   = wave & 3;
    const int quad = lane >> 4;
    const int lc   = lane & 15;
    const int m0l  = wr * 32 + lc;
    const int m1l  = m0l + 16;
    int m0 = row_base + m0l; if (m0 > M - 1) m0 = M - 1;   // clamp for xb reads
    int m1 = row_base + m1l; if (m1 > M - 1) m1 = M - 1;

    const unsigned short* xb_dst = (MODE == 0) ? xb_svc : xb_ep;
    const unsigned short* Xp0 = xb_dst + (size_t)m0 * DF + quad * 8;
    const unsigned short* Xp1 = xb_dst + (size_t)m1 * DF + quad * 8;
    const unsigned short* Bp  = Bpack + lane * 8 + (wc * 2) * 512;

    f32x4 acc0[2], acc1[2];
#pragma unroll
    for (int ct = 0; ct < 2; ++ct) {
        acc0[ct] = (f32x4){0.f, 0.f, 0.f, 0.f};
        acc1[ct] = (f32x4){0.f, 0.f, 0.f, 0.f};
    }

#pragma unroll
    for (int kt = 0; kt < KSTEPS; ++kt) {
        bf16x8 af0, af1;
        if (kt < MKSTEPS) {
            int c = kt * 4 + quad;   // 16 B chunk index
            af0 = *reinterpret_cast<const bf16x8*>(
                smean + m0l * MK + ((c ^ (m0l & 7)) << 3));
            af1 = *reinterpret_cast<const bf16x8*>(
                smean + m1l * MK + ((c ^ (m1l & 7)) << 3));
        } else {
            af0 = *reinterpret_cast<const bf16x8*>(Xp0 + (kt - MKSTEPS) * 32);
            af1 = *reinterpret_cast<const bf16x8*>(Xp1 + (kt - MKSTEPS) * 32);
        }
        const unsigned short* bptr = Bp + (size_t)kt * 8 * 512;
#pragma unroll
        for (int ct = 0; ct < 2; ++ct) {
            bf16x8 bf = *reinterpret_cast<const bf16x8*>(bptr + ct * 512);
            acc0[ct] = __builtin_amdgcn_mfma_f32_16x16x32_bf16(af0, bf, acc0[ct], 0, 0, 0);
            acc1[ct] = __builtin_amdgcn_mfma_f32_16x16x32_bf16(af1, bf, acc1[ct], 0, 0, 0);
        }
    }

    float bc[2];
#pragma unroll
    for (int ct = 0; ct < 2; ++ct) bc[ct] = bias[(wc * 2 + ct) * 16 + lc];

    // C/D layout: col = (wc*2+ct)*16 + lc, row = base + quad*4 + r
    const int row0 = row_base + wr * 32;
#pragma unroll
    for (int half = 0; half < 2; ++half) {
        int orow0 = row0 + half * 16 + quad * 4;
        f32x4* accp = half ? acc1 : acc0;
#pragma unroll
        for (int r = 0; r < 4; ++r) {
            int orow = orow0 + r;
            if (orow < M) {
                float* op = out + (size_t)orow * DF + wc * 32 + lc;
#pragma unroll
                for (int ct = 0; ct < 2; ++ct) op[ct * 16] = accp[ct][r] + bc[ct];
            }
        }
    }
}

// ---------------------------------------------------------------------------
extern "C" void kernel_launch(void* const* d_in, const int* in_sizes, int n_in,
                              void* d_out, int out_size, void* d_ws, size_t ws_size,
                              hipStream_t stream)
{
    const float* x_service  = (const float*)d_in[0];
    const float* x_endpoint = (const float*)d_in[1];
    const int*   ei_calls   = (const int*)d_in[2];
    const int*   ei_has     = (const int*)d_in[3];
    const int*   ei_belongs = (const int*)d_in[4];
    const float* Wl_calls   = (const float*)d_in[5];
    const float* bl_calls   = (const float*)d_in[6];
    const float* Wr_calls   = (const float*)d_in[7];
    const float* Wl_has     = (const float*)d_in[8];
    const float* bl_has     = (const float*)d_in[9];
    const float* Wr_has     = (const float*)d_in[10];
    const float* Wl_belongs = (const float*)d_in[11];
    const float* bl_belongs = (const float*)d_in[12];
    const float* Wr_belongs = (const float*)d_in[13];

    const int n_svc = in_sizes[0] / DF;
    const int n_ep  = in_sizes[1] / DF;
    const int E1 = in_sizes[2] / 2;   // calls
    const int E3 = in_sizes[3] / 2;   // has
    const int E2 = in_sizes[4] / 2;   // belongs
    const int Etot = E1 + E2 + E3;
    const int NT = 2 * n_svc + n_ep;

    int* wsi = (int*)d_ws;
    size_t oi = 0;
    int* cnt   = wsi + oi; oi += NT;
    int* slots = wsi + oi; oi += (size_t)NT * CAP;
    oi = (oi + 3) & ~(size_t)3;   // 16B align

    unsigned short* wsu = (unsigned short*)(wsi + oi);
    size_t ou = 0;
    unsigned short* xb_svc = wsu + ou; ou += (size_t)n_svc * DF;
    unsigned short* xb_ep  = wsu + ou; ou += (size_t)n_ep * DF;
    unsigned short* Bp_svc = wsu + ou; ou += 12 * 8 * 64 * 8;
    unsigned short* Bp_ep  = wsu + ou; ou += 8 * 8 * 64 * 8;
    ou = (ou + 7) & ~(size_t)7;
    float* bias_svc = (float*)(wsu + ou);
    float* bias_ep  = bias_svc + DF;

    // only the degree counters need zero-init
    hipMemsetAsync(cnt, 0, (size_t)NT * sizeof(int), stream);

    const int B_fill = (Etot + 255) / 256;                              // 1 edge/thread
    const int B_pack = (12 * 8 * 64 * 8 + 8 * 8 * 64 * 8 + 255) / 256;  // 320
    int B_conv = (int)(((size_t)(n_svc + n_ep) * 32 + 255) / 256);
    if (B_conv < B_fill) B_conv = B_fill;     // grid must cover fill duty
    if (B_conv < B_pack) B_conv = B_pack;     // and pack duty

    prep_kernel<<<B_conv, 256, 0, stream>>>(
        ei_calls, E1, ei_belongs, E2, ei_has, E3, cnt, slots,
        x_service, x_endpoint, xb_svc, xb_ep, n_svc, n_ep,
        Wl_calls, Wr_calls, Wl_belongs, Wr_belongs, Wl_has, Wr_has,
        bl_calls, bl_belongs, bl_has, Bp_svc, Bp_ep, bias_svc, bias_ep,
        B_fill, B_pack, B_conv);

    float* out_svc = (float*)d_out;
    float* out_ep  = out_svc + (size_t)n_svc * DF;

    fused_gemm<0><<<(n_svc + 63) / 64, 512, 0, stream>>>(
        xb_svc, xb_ep, cnt, slots, Bp_svc, bias_svc, out_svc, n_svc, n_ep);
    fused_gemm<1><<<(n_ep + 63) / 64, 512, 0, stream>>>(
        xb_svc, xb_ep, cnt, slots, Bp_ep, bias_ep, out_ep, n_svc, n_ep);
}